// Round 8
// baseline (224.155 us; speedup 1.0000x reference)
//
#include <hip/hip_runtime.h>
#include <hip/hip_bf16.h>
#include <cstdint>
#include <cstddef>

#define N_NODES 50000
#define N_EDGES 800000
#define DIM 64
#define N_REL 16
#define N_Q 8192
#define NKEY (N_NODES * 16)
#define KDIM 1088   // 16 relations * 64 + 64 self
#define SROW 1096   // padded LDS row in bf16 elems
#define TILE 32     // nodes per block (2 per wave)
#define NKB 34      // K blocks of 32 (KDIM/32)
#define KH 17       // kblocks per k-half
#define WTL (4 * NKB * 512)  // per-layer packed wt elems

// fused-prep grid partition
#define NB_PROJ 12500            // 50000*64/256
#define NB_WPREP 544             // 2*WTL/256
#define NB_ZERO 782              // ceil(200000 uint4 / 256)
#define NSCAN 196                // ceil(NKEY/4096)

typedef __attribute__((ext_vector_type(8))) short bf16x8;
typedef __attribute__((ext_vector_type(4))) float f32x4;

__device__ __forceinline__ float bcast_lane(float v, int l) {
    return __int_as_float(__builtin_amdgcn_readlane(__float_as_int(v), l));
}
__device__ __forceinline__ unsigned short f2bf(float f) {
    unsigned int b = __float_as_uint(f);
    return (unsigned short)((b + 0x7FFFu + ((b >> 16) & 1u)) >> 16);
}
__device__ __forceinline__ float bf2f(unsigned short u) {
    return __uint_as_float(((unsigned int)u) << 16);
}

// ---------- fused prep: input projection + weight pack + cnt zero ----------
__global__ __launch_bounds__(256) void k_prep(
    const float* __restrict__ nf, const float* __restrict__ inw,
    const float* __restrict__ inb, unsigned short* __restrict__ xbf,
    const float* __restrict__ rel_w, const float* __restrict__ self_w,
    unsigned short* __restrict__ wt, int* __restrict__ cnt)
{
    const int b = blockIdx.x, tid = threadIdx.x;
    if (b < NB_PROJ) {
        int t = b * 256 + tid;
        int n = t >> 6, o = t & 63;
        float4 f = *reinterpret_cast<const float4*>(nf + (size_t)n * 4);
        float a = inb[o] + f.x * inw[o] + f.y * inw[64 + o] + f.z * inw[128 + o] + f.w * inw[192 + o];
        xbf[t] = f2bf(a > 0.f ? a : 0.f);
    } else if (b < NB_PROJ + NB_WPREP) {
        int i = (b - NB_PROJ) * 256 + tid;
        int j = i & 7;
        int lane = (i >> 3) & 63;
        int rest = i >> 9;          // l*136 + g*34 + t
        int t = rest % NKB;
        int gl = rest / NKB;
        int g = gl & 3;
        int l = gl >> 2;
        int col = g * 16 + (lane & 15);
        int k = t * 32 + (lane >> 4) * 8 + j;
        float v;
        if (k < 1024) {
            int r = k >> 6, d = k & 63;
            v = rel_w[(((size_t)l * 16 + r) * 64 + d) * 64 + col];
        } else {
            int d = k - 1024;
            v = self_w[((size_t)l * 64 + d) * 64 + col];
        }
        wt[i] = f2bf(v);
    } else {
        int i = (b - NB_PROJ - NB_WPREP) * 256 + tid;
        if (i < NKEY / 4)
            reinterpret_cast<uint4*>(cnt)[i] = make_uint4(0, 0, 0, 0);
    }
}

// ---------- CSR build over key = dst*16 + rel ----------
__global__ __launch_bounds__(256) void k_hist16(
    const int* __restrict__ dst, const int* __restrict__ et, int* __restrict__ cnt)
{
    int e = blockIdx.x * 256 + threadIdx.x;
    if (e < N_EDGES) atomicAdd(&cnt[dst[e] * 16 + et[e]], 1);
}

__global__ __launch_bounds__(256) void k_scanA(
    const int* __restrict__ cnt, int* __restrict__ offs, int* __restrict__ part)
{
    int t = threadIdx.x;
    size_t base = (size_t)blockIdx.x * 4096 + (size_t)t * 16;
    bool ok = base < (size_t)NKEY;
    int v[16];
    if (ok) {
        #pragma unroll
        for (int q = 0; q < 4; ++q)
            *reinterpret_cast<int4*>(&v[q * 4]) = *reinterpret_cast<const int4*>(&cnt[base + q * 4]);
    } else {
        #pragma unroll
        for (int j = 0; j < 16; ++j) v[j] = 0;
    }
    int run = 0;
    #pragma unroll
    for (int j = 0; j < 16; ++j) { int c = v[j]; v[j] = run; run += c; }
    int lane = t & 63, wid = t >> 6;
    int incl = run;
    #pragma unroll
    for (int o = 1; o < 64; o <<= 1) { int u = __shfl_up(incl, o); if (lane >= o) incl += u; }
    __shared__ int wtot[4], wbase[4];
    if (lane == 63) wtot[wid] = incl;
    __syncthreads();
    if (t == 0) { int r = 0; for (int w = 0; w < 4; ++w) { wbase[w] = r; r += wtot[w]; } part[blockIdx.x] = r; }
    __syncthreads();
    int texcl = wbase[wid] + incl - run;
    if (ok) {
        #pragma unroll
        for (int j = 0; j < 16; ++j) offs[base + j] = texcl + v[j];
    }
}

// scanC with inlined partial-prefix (replaces scanB+scanC): every block
// block-reduces the ≤196 partials it needs — removes the serial scanB dispatch.
__global__ __launch_bounds__(256) void k_scanC(
    int* __restrict__ offs, const int* __restrict__ part, int* __restrict__ woffs)
{
    const int t = threadIdx.x;
    const int i = blockIdx.x * 256 + t;
    const int b0 = (blockIdx.x * 256) >> 12;
    const int b1 = (blockIdx.x * 256 + 255) >> 12;
    int v = (t < b0) ? part[t] : 0;   // NSCAN <= 256
    // block reduce sum
    #pragma unroll
    for (int o = 32; o > 0; o >>= 1) v += __shfl_xor(v, o);
    __shared__ int red[4];
    if ((t & 63) == 0) red[t >> 6] = v;
    __syncthreads();
    int pre0 = red[0] + red[1] + red[2] + red[3];
    int pre = ((i >> 12) == b0 || b1 == b0) ? pre0 : (pre0 + part[b0]);
    if (i < NKEY) {
        int val = offs[i] + pre;
        offs[i] = val;
        woffs[i] = val;
    } else if (i == NKEY) {
        offs[i] = N_EDGES;
    }
}

__global__ __launch_bounds__(256) void k_fill16(
    const int* __restrict__ src, const int* __restrict__ dst, const int* __restrict__ et,
    int* __restrict__ woffs, unsigned int* __restrict__ csr)
{
    int e = blockIdx.x * 256 + threadIdx.x;
    if (e >= N_EDGES) return;
    int key = dst[e] * 16 + et[e];
    int pos = atomicAdd(&woffs[key], 1);
    csr[pos] = ((unsigned)src[e] << 4) | (unsigned)et[e];
}

// ---------- fused layer: 32 nodes/block, 16 waves; flat 2-node gather; 16-wave MFMA ----------
__global__ __launch_bounds__(1024, 8) void k_layer(
    const unsigned short* __restrict__ xbf_in,
    const int* __restrict__ offs,
    const unsigned int* __restrict__ csr,
    const unsigned short* __restrict__ wt,    // this layer, packed: [4][34][64][8] bf16
    const float* __restrict__ selfb,          // [64]
    unsigned short* __restrict__ xbf_out)
{
    alignas(16) __shared__ unsigned short S[TILE * SROW];
    const int tid = threadIdx.x, lane = tid & 63;
    const int wid = __builtin_amdgcn_readfirstlane(tid >> 6);
    const int nb = blockIdx.x * TILE;
    const int node0 = nb + wid * 2;   // node1 = node0+1 (valid iff node0 valid; N_NODES even)

    // zero own 2 S rows (elems 0..1087 incl. self slot)
    #pragma unroll
    for (int s = 0; s < 2; ++s) {
        unsigned int* Sr = reinterpret_cast<unsigned int*>(&S[(wid * 2 + s) * SROW]);
        #pragma unroll
        for (int i = 0; i < 8; ++i) Sr[lane + i * 64] = 0u;
        if (lane < 32) Sr[512 + lane] = 0u;
    }

    // phase A: flat gather over the wave's contiguous 2-node csr range
    if (node0 < N_NODES) {
        const int kb = node0 * 16;
        const int A = offs[kb];
        const int M = offs[kb + 16];
        const int B = offs[kb + 32];
        S[(wid * 2) * SROW + 1024 + lane] = xbf_in[(size_t)node0 * 64 + lane];
        S[(wid * 2 + 1) * SROW + 1024 + lane] = xbf_in[(size_t)(node0 + 1) * 64 + lane];
        const int d0 = M - A, d1 = B - M;
        const float inv0 = 1.0f / (float)(d0 > 1 ? d0 : 1);
        const float inv1 = 1.0f / (float)(d1 > 1 ? d1 : 1);
        int curkey = -1;
        float acc = 0.f, curinv = inv0;
        for (int e = A; e < B; e += 16) {
            unsigned cvs[16];
            float xv[16];
            #pragma unroll
            for (int j = 0; j < 16; ++j) {
                int idx = e + j;
                idx = idx < B - 1 ? idx : B - 1;   // clamp inside wave range
                cvs[j] = csr[idx];
            }
            #pragma unroll
            for (int j = 0; j < 16; ++j)
                xv[j] = bf2f(xbf_in[(size_t)(cvs[j] >> 4) * 64 + lane]);
            #pragma unroll
            for (int j = 0; j < 16; ++j) {
                if (e + j < B) {
                    int keyj = (int)(cvs[j] & 15u) | ((e + j) >= M ? 16 : 0);
                    if (keyj != curkey) {
                        if (curkey >= 0) {
                            int row = wid * 2 + (curkey >> 4);
                            S[row * SROW + (curkey & 15) * 64 + lane] = f2bf(acc * curinv);
                        }
                        curkey = keyj;
                        acc = 0.f;
                        curinv = (keyj >= 16) ? inv1 : inv0;
                    }
                    acc += xv[j];
                }
            }
        }
        if (curkey >= 0) {
            int row = wid * 2 + (curkey >> 4);
            S[row * SROW + (curkey & 15) * 64 + lane] = f2bf(acc * curinv);
        }
    }
    __syncthreads();

    // phase B: 16 waves: (colgroup g, mtile mt, khalf kh); 17 kblocks each
    const int g = wid & 3, mt = (wid >> 2) & 1, kh = wid >> 3;
    const int colg = lane & 15, kg = lane >> 4;
    f32x4 acc4 = {0.f, 0.f, 0.f, 0.f};
    const unsigned short* wb = wt + (size_t)g * (NKB * 512) + (size_t)lane * 8 + (size_t)kh * KH * 512;
    const unsigned short* sa = &S[(mt * 16 + colg) * SROW + kg * 8 + kh * KH * 32];
    #pragma unroll 2
    for (int t = 0; t < KH; ++t) {
        bf16x8 b = *reinterpret_cast<const bf16x8*>(wb + (size_t)t * 512);
        bf16x8 a = *reinterpret_cast<const bf16x8*>(sa + t * 32);
        acc4 = __builtin_amdgcn_mfma_f32_16x16x32_bf16(a, b, acc4, 0, 0, 0);
    }
    __syncthreads();
    float4* scratch = reinterpret_cast<float4*>(S);
    if (kh == 1) {
        scratch[(wid - 8) * 64 + lane] = make_float4(acc4[0], acc4[1], acc4[2], acc4[3]);
    }
    __syncthreads();
    if (kh == 0) {
        float4 p = scratch[wid * 64 + lane];
        const int col = g * 16 + colg;
        const float sb = selfb[col];
        float vj[4] = {acc4[0] + p.x, acc4[1] + p.y, acc4[2] + p.z, acc4[3] + p.w};
        #pragma unroll
        for (int j = 0; j < 4; ++j) {
            int n0 = nb + mt * 16 + kg * 4 + j;
            float v = vj[j] + sb;
            v = v > 0.f ? v : 0.f;
            if (n0 < N_NODES) xbf_out[(size_t)n0 * 64 + col] = f2bf(v);
        }
    }
}

// ---------- scoring (reads bf16 x) ----------
__global__ __launch_bounds__(256) void k_score(
    const unsigned short* __restrict__ x, const int* __restrict__ heads,
    const int* __restrict__ rels, const int* __restrict__ tails,
    const float* __restrict__ rel_emb, const float* __restrict__ w1,
    const float* __restrict__ b1, const float* __restrict__ w2,
    const float* __restrict__ b2, float* __restrict__ out)
{
    int q = blockIdx.x * 4 + (threadIdx.x >> 6);
    if (q >= N_Q) return;
    int lane = threadIdx.x & 63;
    float zh = bf2f(x[(size_t)heads[q] * 64 + lane]);
    float zt = bf2f(x[(size_t)tails[q] * 64 + lane]);
    float re = rel_emb[(size_t)rels[q] * 64 + lane];
    float acc = b1[lane];
    #pragma unroll 8
    for (int k = 0; k < 64; ++k)
        acc += bcast_lane(zh, k) * w1[k * 64 + lane];
    #pragma unroll 8
    for (int k = 0; k < 64; ++k)
        acc += bcast_lane(zt, k) * w1[(64 + k) * 64 + lane];
    #pragma unroll 8
    for (int k = 0; k < 64; ++k)
        acc += bcast_lane(re, k) * w1[(128 + k) * 64 + lane];
    float h = acc > 0.f ? acc : 0.f;
    float p = h * w2[lane];
    #pragma unroll
    for (int off = 32; off > 0; off >>= 1) p += __shfl_xor(p, off);
    if (lane == 0) out[q] = p + b2[0];
}

// ---------- launch ----------
extern "C" void kernel_launch(void* const* d_in, const int* in_sizes, int n_in,
                              void* d_out, int out_size, void* d_ws, size_t ws_size,
                              hipStream_t stream)
{
    const float* node_feat = (const float*)d_in[0];
    const int* edge_index  = (const int*)d_in[1];
    const int* edge_type   = (const int*)d_in[2];
    const int* heads       = (const int*)d_in[3];
    const int* rels        = (const int*)d_in[4];
    const int* tails       = (const int*)d_in[5];
    const float* in_w      = (const float*)d_in[6];
    const float* in_b      = (const float*)d_in[7];
    const float* rel_w     = (const float*)d_in[8];
    const float* self_w    = (const float*)d_in[9];
    const float* self_b    = (const float*)d_in[10];
    const float* rel_emb   = (const float*)d_in[11];
    const float* sc_w1     = (const float*)d_in[12];
    const float* sc_b1     = (const float*)d_in[13];
    const float* sc_w2     = (const float*)d_in[14];
    const float* sc_b2     = (const float*)d_in[15];
    float* out = (float*)d_out;

    char* ws = (char*)d_ws;
    size_t off = 0;
    auto alloc = [&](size_t bytes) -> void* {
        void* p = ws + off;
        off = (off + bytes + 255) & ~(size_t)255;
        return p;
    };
    unsigned short* xbf_a = (unsigned short*)alloc((size_t)N_NODES * 64 * 2);
    unsigned short* xbf_b = (unsigned short*)alloc((size_t)N_NODES * 64 * 2);
    int* cnt              = (int*)alloc((size_t)NKEY * 4);
    int* offs             = (int*)alloc((size_t)(NKEY + 1) * 4);
    int* woffs            = (int*)alloc((size_t)NKEY * 4);
    unsigned int* csr     = (unsigned int*)alloc((size_t)N_EDGES * 4);
    unsigned short* wt    = (unsigned short*)alloc((size_t)2 * WTL * 2);
    int* part             = (int*)alloc(1024);

    const int* src = edge_index;
    const int* dst = edge_index + N_EDGES;

    k_prep<<<NB_PROJ + NB_WPREP + NB_ZERO, 256, 0, stream>>>(
        node_feat, in_w, in_b, xbf_a, rel_w, self_w, wt, cnt);
    k_hist16<<<(N_EDGES + 255) / 256, 256, 0, stream>>>(dst, edge_type, cnt);
    k_scanA<<<NSCAN, 256, 0, stream>>>(cnt, offs, part);
    k_scanC<<<(NKEY + 1 + 255) / 256, 256, 0, stream>>>(offs, part, woffs);
    k_fill16<<<(N_EDGES + 255) / 256, 256, 0, stream>>>(src, dst, edge_type, woffs, csr);

    for (int l = 0; l < 2; ++l) {
        const unsigned short* xin = (l == 0) ? xbf_a : xbf_b;
        unsigned short* xout = (l == 0) ? xbf_b : xbf_a;
        k_layer<<<(N_NODES + TILE - 1) / TILE, 1024, 0, stream>>>(
            xin, offs, csr, wt + (size_t)l * WTL, self_b + l * 64, xout);
    }
    k_score<<<(N_Q + 3) / 4, 256, 0, stream>>>(xbf_a, heads, rels, tails, rel_emb,
                                               sc_w1, sc_b1, sc_w2, sc_b2, out);
}

// Round 9
// 212.384 us; speedup vs baseline: 1.0554x; 1.0554x over previous
//
#include <hip/hip_runtime.h>
#include <hip/hip_bf16.h>
#include <cstdint>
#include <cstddef>

#define N_NODES 50000
#define N_EDGES 800000
#define DIM 64
#define N_REL 16
#define N_Q 8192
#define NKEY (N_NODES * 16)
#define KDIM 1088   // 16 relations * 64 + 64 self
#define SROW 1096   // padded LDS row in bf16 elems
#define TILE 32     // nodes per block (2 per wave)
#define NKB 34      // K blocks of 32 (KDIM/32)
#define WTL (4 * NKB * 512)  // per-layer packed wt elems

// fused-prep grid partition
#define NB_PROJ 12500            // 50000*64/256
#define NB_WPREP 544             // 2*WTL/256
#define NB_ZERO 782              // ceil(200000 uint4 / 256)
#define NSCAN 196                // ceil(NKEY/4096)

typedef __attribute__((ext_vector_type(8))) short bf16x8;
typedef __attribute__((ext_vector_type(4))) float f32x4;

__device__ __forceinline__ float bcast_lane(float v, int l) {
    return __int_as_float(__builtin_amdgcn_readlane(__float_as_int(v), l));
}
__device__ __forceinline__ unsigned short f2bf(float f) {
    unsigned int b = __float_as_uint(f);
    return (unsigned short)((b + 0x7FFFu + ((b >> 16) & 1u)) >> 16);
}
__device__ __forceinline__ float bf2f(unsigned short u) {
    return __uint_as_float(((unsigned int)u) << 16);
}

// ---------- fused prep: input projection + weight pack + cnt zero ----------
__global__ __launch_bounds__(256) void k_prep(
    const float* __restrict__ nf, const float* __restrict__ inw,
    const float* __restrict__ inb, unsigned short* __restrict__ xbf,
    const float* __restrict__ rel_w, const float* __restrict__ self_w,
    unsigned short* __restrict__ wt, int* __restrict__ cnt)
{
    const int b = blockIdx.x, tid = threadIdx.x;
    if (b < NB_PROJ) {
        int t = b * 256 + tid;
        int n = t >> 6, o = t & 63;
        float4 f = *reinterpret_cast<const float4*>(nf + (size_t)n * 4);
        float a = inb[o] + f.x * inw[o] + f.y * inw[64 + o] + f.z * inw[128 + o] + f.w * inw[192 + o];
        xbf[t] = f2bf(a > 0.f ? a : 0.f);
    } else if (b < NB_PROJ + NB_WPREP) {
        int i = (b - NB_PROJ) * 256 + tid;
        int j = i & 7;
        int lane = (i >> 3) & 63;
        int rest = i >> 9;          // l*136 + g*34 + t
        int t = rest % NKB;
        int gl = rest / NKB;
        int g = gl & 3;
        int l = gl >> 2;
        int col = g * 16 + (lane & 15);
        int k = t * 32 + (lane >> 4) * 8 + j;
        float v;
        if (k < 1024) {
            int r = k >> 6, d = k & 63;
            v = rel_w[(((size_t)l * 16 + r) * 64 + d) * 64 + col];
        } else {
            int d = k - 1024;
            v = self_w[((size_t)l * 64 + d) * 64 + col];
        }
        wt[i] = f2bf(v);
    } else {
        int i = (b - NB_PROJ - NB_WPREP) * 256 + tid;
        if (i < NKEY / 4)
            reinterpret_cast<uint4*>(cnt)[i] = make_uint4(0, 0, 0, 0);
    }
}

// ---------- CSR build over key = dst*16 + rel ----------
__global__ __launch_bounds__(256) void k_hist16(
    const int* __restrict__ dst, const int* __restrict__ et, int* __restrict__ cnt)
{
    int e = blockIdx.x * 256 + threadIdx.x;
    if (e < N_EDGES) atomicAdd(&cnt[dst[e] * 16 + et[e]], 1);
}

__global__ __launch_bounds__(256) void k_scanA(
    const int* __restrict__ cnt, int* __restrict__ offs, int* __restrict__ part)
{
    int t = threadIdx.x;
    size_t base = (size_t)blockIdx.x * 4096 + (size_t)t * 16;
    bool ok = base < (size_t)NKEY;
    int v[16];
    if (ok) {
        #pragma unroll
        for (int q = 0; q < 4; ++q)
            *reinterpret_cast<int4*>(&v[q * 4]) = *reinterpret_cast<const int4*>(&cnt[base + q * 4]);
    } else {
        #pragma unroll
        for (int j = 0; j < 16; ++j) v[j] = 0;
    }
    int run = 0;
    #pragma unroll
    for (int j = 0; j < 16; ++j) { int c = v[j]; v[j] = run; run += c; }
    int lane = t & 63, wid = t >> 6;
    int incl = run;
    #pragma unroll
    for (int o = 1; o < 64; o <<= 1) { int u = __shfl_up(incl, o); if (lane >= o) incl += u; }
    __shared__ int wtot[4], wbase[4];
    if (lane == 63) wtot[wid] = incl;
    __syncthreads();
    if (t == 0) { int r = 0; for (int w = 0; w < 4; ++w) { wbase[w] = r; r += wtot[w]; } part[blockIdx.x] = r; }
    __syncthreads();
    int texcl = wbase[wid] + incl - run;
    if (ok) {
        #pragma unroll
        for (int j = 0; j < 16; ++j) offs[base + j] = texcl + v[j];
    }
}

// scanC with inlined partial-prefix (replaces scanB+scanC)
__global__ __launch_bounds__(256) void k_scanC(
    int* __restrict__ offs, const int* __restrict__ part, int* __restrict__ woffs)
{
    const int t = threadIdx.x;
    const int i = blockIdx.x * 256 + t;
    const int b0 = (blockIdx.x * 256) >> 12;
    int v = (t < b0) ? part[t] : 0;   // NSCAN <= 256
    #pragma unroll
    for (int o = 32; o > 0; o >>= 1) v += __shfl_xor(v, o);
    __shared__ int red[4];
    if ((t & 63) == 0) red[t >> 6] = v;
    __syncthreads();
    int pre = red[0] + red[1] + red[2] + red[3];
    if (i < NKEY) {
        int val = offs[i] + pre;
        offs[i] = val;
        woffs[i] = val;
    } else if (i == NKEY) {
        offs[i] = N_EDGES;
    }
}

__global__ __launch_bounds__(256) void k_fill16(
    const int* __restrict__ src, const int* __restrict__ dst, const int* __restrict__ et,
    int* __restrict__ woffs, unsigned int* __restrict__ csr)
{
    int e = blockIdx.x * 256 + threadIdx.x;
    if (e >= N_EDGES) return;
    int key = dst[e] * 16 + et[e];
    int pos = atomicAdd(&woffs[key], 1);
    csr[pos] = ((unsigned)src[e] << 4) | (unsigned)et[e];
}

// ---------- fused layer: 32 nodes/block, 16 waves ----------
// phase A: per-node gather, 8-deep double-buffered pipeline
// phase B: 16 waves = (4 colgroups) x (4 K-quarters), each does BOTH m-tiles
__global__ __launch_bounds__(1024, 8) void k_layer(
    const unsigned short* __restrict__ xbf_in,
    const int* __restrict__ offs,
    const unsigned int* __restrict__ csr,
    const unsigned short* __restrict__ wt,    // this layer, packed: [4][34][64][8] bf16
    const float* __restrict__ selfb,          // [64]
    unsigned short* __restrict__ xbf_out)
{
    alignas(16) __shared__ unsigned short S[TILE * SROW];
    const int tid = threadIdx.x, lane = tid & 63;
    const int wid = __builtin_amdgcn_readfirstlane(tid >> 6);
    const int nb = blockIdx.x * TILE;

    // zero own 2 S rows (elems 0..1087 incl. self slot)
    #pragma unroll
    for (int s = 0; s < 2; ++s) {
        unsigned int* Sr = reinterpret_cast<unsigned int*>(&S[(wid * 2 + s) * SROW]);
        #pragma unroll
        for (int i = 0; i < 8; ++i) Sr[lane + i * 64] = 0u;
        if (lane < 32) Sr[512 + lane] = 0u;
    }

    // phase A
    #pragma unroll 1
    for (int s = 0; s < 2; ++s) {
        const int nl = wid * 2 + s;
        const int node = nb + nl;
        if (node >= N_NODES) break;
        const int A = offs[node * 16];
        const int B = offs[node * 16 + 16];
        S[nl * SROW + 1024 + lane] = xbf_in[(size_t)node * 64 + lane];
        const int deg = B - A;
        if (deg <= 0) continue;
        const float inv = 1.0f / (float)(deg > 1 ? deg : 1);

        unsigned c0[8], c1[8];
        float x0[8], x1[8];
        int cur = -1;
        float acc = 0.f;

        auto loadb = [&](unsigned (&cv)[8], float (&xv)[8], int eb) {
            #pragma unroll
            for (int j = 0; j < 8; ++j) {
                int idx = eb + j;
                idx = idx < B - 1 ? idx : B - 1;
                cv[j] = csr[idx];
            }
            #pragma unroll
            for (int j = 0; j < 8; ++j)
                xv[j] = bf2f(xbf_in[(size_t)(cv[j] >> 4) * 64 + lane]);
        };
        auto accum = [&](unsigned (&cv)[8], float (&xv)[8], int m) {
            #pragma unroll
            for (int j = 0; j < 8; ++j) {
                if (j < m) {
                    int rj = (int)(cv[j] & 15u);
                    if (rj != cur) {
                        if (cur >= 0) S[nl * SROW + cur * 64 + lane] = f2bf(acc * inv);
                        cur = rj;
                        acc = 0.f;
                    }
                    acc += xv[j];
                }
            }
        };

        int e0 = A;
        int m0 = deg > 8 ? 8 : deg;
        loadb(c0, x0, e0);
        for (;;) {
            int e1 = e0 + 8;
            int m1 = B - e1;
            m1 = m1 > 8 ? 8 : m1;
            if (m1 > 0) loadb(c1, x1, e1);
            accum(c0, x0, m0);
            if (m1 <= 0) break;
            int e2 = e1 + 8;
            m0 = B - e2;
            m0 = m0 > 8 ? 8 : m0;
            if (m0 > 0) loadb(c0, x0, e2);
            accum(c1, x1, m1);
            if (m0 <= 0) break;
            e0 = e2;
        }
        if (cur >= 0) S[nl * SROW + cur * 64 + lane] = f2bf(acc * inv);
    }
    __syncthreads();

    // phase B: wave = (g, kq); K-quarters {9,9,8,8}; both m-tiles per wave
    const int g = wid & 3, kq = wid >> 2;
    const int t0 = kq * 8 + (kq < 2 ? kq : 2);   // 0,9,18,26
    const int tn = kq < 2 ? 9 : 8;
    const int colg = lane & 15, kg = lane >> 4;
    f32x4 acc0 = {0.f, 0.f, 0.f, 0.f};
    f32x4 acc1 = {0.f, 0.f, 0.f, 0.f};
    const unsigned short* wb = wt + (size_t)g * (NKB * 512) + (size_t)lane * 8 + (size_t)t0 * 512;
    const unsigned short* sa0 = &S[colg * SROW + kg * 8 + t0 * 32];
    const unsigned short* sa1 = &S[(16 + colg) * SROW + kg * 8 + t0 * 32];
    #pragma unroll 1
    for (int t = 0; t < tn; ++t) {
        bf16x8 b  = *reinterpret_cast<const bf16x8*>(wb + (size_t)t * 512);
        bf16x8 a0 = *reinterpret_cast<const bf16x8*>(sa0 + t * 32);
        bf16x8 a1 = *reinterpret_cast<const bf16x8*>(sa1 + t * 32);
        acc0 = __builtin_amdgcn_mfma_f32_16x16x32_bf16(a0, b, acc0, 0, 0, 0);
        acc1 = __builtin_amdgcn_mfma_f32_16x16x32_bf16(a1, b, acc1, 0, 0, 0);
    }
    __syncthreads();
    float4* scr = reinterpret_cast<float4*>(S);
    if (kq > 0) {
        int base = ((kq - 1) * 4 + g) * 128 + lane;
        scr[base]      = make_float4(acc0[0], acc0[1], acc0[2], acc0[3]);
        scr[base + 64] = make_float4(acc1[0], acc1[1], acc1[2], acc1[3]);
    }
    __syncthreads();
    if (kq == 0) {
        #pragma unroll
        for (int p = 0; p < 3; ++p) {
            int base = (p * 4 + g) * 128 + lane;
            float4 q0 = scr[base], q1 = scr[base + 64];
            acc0[0] += q0.x; acc0[1] += q0.y; acc0[2] += q0.z; acc0[3] += q0.w;
            acc1[0] += q1.x; acc1[1] += q1.y; acc1[2] += q1.z; acc1[3] += q1.w;
        }
        const int col = g * 16 + colg;
        const float sb = selfb[col];
        #pragma unroll
        for (int j = 0; j < 4; ++j) {
            int n0 = nb + kg * 4 + j;
            float v0 = acc0[j] + sb;
            v0 = v0 > 0.f ? v0 : 0.f;
            if (n0 < N_NODES) xbf_out[(size_t)n0 * 64 + col] = f2bf(v0);
            int n1 = nb + 16 + kg * 4 + j;
            float v1 = acc1[j] + sb;
            v1 = v1 > 0.f ? v1 : 0.f;
            if (n1 < N_NODES) xbf_out[(size_t)n1 * 64 + col] = f2bf(v1);
        }
    }
}

// ---------- scoring (reads bf16 x) ----------
__global__ __launch_bounds__(256) void k_score(
    const unsigned short* __restrict__ x, const int* __restrict__ heads,
    const int* __restrict__ rels, const int* __restrict__ tails,
    const float* __restrict__ rel_emb, const float* __restrict__ w1,
    const float* __restrict__ b1, const float* __restrict__ w2,
    const float* __restrict__ b2, float* __restrict__ out)
{
    int q = blockIdx.x * 4 + (threadIdx.x >> 6);
    if (q >= N_Q) return;
    int lane = threadIdx.x & 63;
    float zh = bf2f(x[(size_t)heads[q] * 64 + lane]);
    float zt = bf2f(x[(size_t)tails[q] * 64 + lane]);
    float re = rel_emb[(size_t)rels[q] * 64 + lane];
    float acc = b1[lane];
    #pragma unroll 8
    for (int k = 0; k < 64; ++k)
        acc += bcast_lane(zh, k) * w1[k * 64 + lane];
    #pragma unroll 8
    for (int k = 0; k < 64; ++k)
        acc += bcast_lane(zt, k) * w1[(64 + k) * 64 + lane];
    #pragma unroll 8
    for (int k = 0; k < 64; ++k)
        acc += bcast_lane(re, k) * w1[(128 + k) * 64 + lane];
    float h = acc > 0.f ? acc : 0.f;
    float p = h * w2[lane];
    #pragma unroll
    for (int off = 32; off > 0; off >>= 1) p += __shfl_xor(p, off);
    if (lane == 0) out[q] = p + b2[0];
}

// ---------- launch ----------
extern "C" void kernel_launch(void* const* d_in, const int* in_sizes, int n_in,
                              void* d_out, int out_size, void* d_ws, size_t ws_size,
                              hipStream_t stream)
{
    const float* node_feat = (const float*)d_in[0];
    const int* edge_index  = (const int*)d_in[1];
    const int* edge_type   = (const int*)d_in[2];
    const int* heads       = (const int*)d_in[3];
    const int* rels        = (const int*)d_in[4];
    const int* tails       = (const int*)d_in[5];
    const float* in_w      = (const float*)d_in[6];
    const float* in_b      = (const float*)d_in[7];
    const float* rel_w     = (const float*)d_in[8];
    const float* self_w    = (const float*)d_in[9];
    const float* self_b    = (const float*)d_in[10];
    const float* rel_emb   = (const float*)d_in[11];
    const float* sc_w1     = (const float*)d_in[12];
    const float* sc_b1     = (const float*)d_in[13];
    const float* sc_w2     = (const float*)d_in[14];
    const float* sc_b2     = (const float*)d_in[15];
    float* out = (float*)d_out;

    char* ws = (char*)d_ws;
    size_t off = 0;
    auto alloc = [&](size_t bytes) -> void* {
        void* p = ws + off;
        off = (off + bytes + 255) & ~(size_t)255;
        return p;
    };
    unsigned short* xbf_a = (unsigned short*)alloc((size_t)N_NODES * 64 * 2);
    unsigned short* xbf_b = (unsigned short*)alloc((size_t)N_NODES * 64 * 2);
    int* cnt              = (int*)alloc((size_t)NKEY * 4);
    int* offs             = (int*)alloc((size_t)(NKEY + 1) * 4);
    int* woffs            = (int*)alloc((size_t)NKEY * 4);
    unsigned int* csr     = (unsigned int*)alloc((size_t)N_EDGES * 4);
    unsigned short* wt    = (unsigned short*)alloc((size_t)2 * WTL * 2);
    int* part             = (int*)alloc(1024);

    const int* src = edge_index;
    const int* dst = edge_index + N_EDGES;

    k_prep<<<NB_PROJ + NB_WPREP + NB_ZERO, 256, 0, stream>>>(
        node_feat, in_w, in_b, xbf_a, rel_w, self_w, wt, cnt);
    k_hist16<<<(N_EDGES + 255) / 256, 256, 0, stream>>>(dst, edge_type, cnt);
    k_scanA<<<NSCAN, 256, 0, stream>>>(cnt, offs, part);
    k_scanC<<<(NKEY + 1 + 255) / 256, 256, 0, stream>>>(offs, part, woffs);
    k_fill16<<<(N_EDGES + 255) / 256, 256, 0, stream>>>(src, dst, edge_type, woffs, csr);

    for (int l = 0; l < 2; ++l) {
        const unsigned short* xin = (l == 0) ? xbf_a : xbf_b;
        unsigned short* xout = (l == 0) ? xbf_b : xbf_a;
        k_layer<<<(N_NODES + TILE - 1) / TILE, 1024, 0, stream>>>(
            xin, offs, csr, wt + (size_t)l * WTL, self_b + l * 64, xout);
    }
    k_score<<<(N_Q + 3) / 4, 256, 0, stream>>>(xbf_a, heads, rels, tails, rel_emb,
                                               sc_w1, sc_b1, sc_w2, sc_b2, out);
}

// Round 10
// 187.796 us; speedup vs baseline: 1.1936x; 1.1309x over previous
//
#include <hip/hip_runtime.h>
#include <hip/hip_bf16.h>
#include <cstdint>
#include <cstddef>

#define N_NODES 50000
#define N_EDGES 800000
#define DIM 64
#define N_REL 16
#define N_Q 8192
#define NKEY (N_NODES * 16)
#define KDIM 1088   // 16 relations * 64 + 64 self
#define SROW 1096   // padded LDS row in bf16 elems
#define TILE 32     // nodes per block (2 per wave)
#define NKB 34      // K blocks of 32 (KDIM/32)
#define WTL (4 * NKB * 512)  // per-layer packed wt elems
#define NBKT 196    // coarse buckets (dst>>8)

// fused-prep grid partition
#define NB_PROJ 12500            // 50000*64/256
#define NB_WPREP 544             // 2*WTL/256
#define NB_ZERO 782              // ceil(200000 uint4 / 256)
#define NSCAN 196                // ceil(NKEY/4096)

typedef __attribute__((ext_vector_type(8))) short bf16x8;
typedef __attribute__((ext_vector_type(4))) float f32x4;

__device__ __forceinline__ float bcast_lane(float v, int l) {
    return __int_as_float(__builtin_amdgcn_readlane(__float_as_int(v), l));
}
__device__ __forceinline__ unsigned short f2bf(float f) {
    unsigned int b = __float_as_uint(f);
    return (unsigned short)((b + 0x7FFFu + ((b >> 16) & 1u)) >> 16);
}
__device__ __forceinline__ float bf2f(unsigned short u) {
    return __uint_as_float(((unsigned int)u) << 16);
}

// ---------- fused prep: input projection + weight pack + cnt zero ----------
__global__ __launch_bounds__(256) void k_prep(
    const float* __restrict__ nf, const float* __restrict__ inw,
    const float* __restrict__ inb, unsigned short* __restrict__ xbf,
    const float* __restrict__ rel_w, const float* __restrict__ self_w,
    unsigned short* __restrict__ wt, int* __restrict__ cnt)
{
    const int b = blockIdx.x, tid = threadIdx.x;
    if (b < NB_PROJ) {
        int t = b * 256 + tid;
        int n = t >> 6, o = t & 63;
        float4 f = *reinterpret_cast<const float4*>(nf + (size_t)n * 4);
        float a = inb[o] + f.x * inw[o] + f.y * inw[64 + o] + f.z * inw[128 + o] + f.w * inw[192 + o];
        xbf[t] = f2bf(a > 0.f ? a : 0.f);
    } else if (b < NB_PROJ + NB_WPREP) {
        int i = (b - NB_PROJ) * 256 + tid;
        int j = i & 7;
        int lane = (i >> 3) & 63;
        int rest = i >> 9;          // l*136 + g*34 + t
        int t = rest % NKB;
        int gl = rest / NKB;
        int g = gl & 3;
        int l = gl >> 2;
        int col = g * 16 + (lane & 15);
        int k = t * 32 + (lane >> 4) * 8 + j;
        float v;
        if (k < 1024) {
            int r = k >> 6, d = k & 63;
            v = rel_w[(((size_t)l * 16 + r) * 64 + d) * 64 + col];
        } else {
            int d = k - 1024;
            v = self_w[((size_t)l * 64 + d) * 64 + col];
        }
        wt[i] = f2bf(v);
    } else {
        int i = (b - NB_PROJ - NB_WPREP) * 256 + tid;
        if (i < NKEY / 4)
            reinterpret_cast<uint4*>(cnt)[i] = make_uint4(0, 0, 0, 0);
    }
}

// ---------- CSR build over key = dst*16 + rel ----------
__global__ __launch_bounds__(256) void k_hist16(
    const int* __restrict__ dst, const int* __restrict__ et, int* __restrict__ cnt)
{
    int e = blockIdx.x * 256 + threadIdx.x;
    if (e < N_EDGES) atomicAdd(&cnt[dst[e] * 16 + et[e]], 1);
}

__global__ __launch_bounds__(256) void k_scanA(
    const int* __restrict__ cnt, int* __restrict__ offs, int* __restrict__ part)
{
    int t = threadIdx.x;
    size_t base = (size_t)blockIdx.x * 4096 + (size_t)t * 16;
    bool ok = base < (size_t)NKEY;
    int v[16];
    if (ok) {
        #pragma unroll
        for (int q = 0; q < 4; ++q)
            *reinterpret_cast<int4*>(&v[q * 4]) = *reinterpret_cast<const int4*>(&cnt[base + q * 4]);
    } else {
        #pragma unroll
        for (int j = 0; j < 16; ++j) v[j] = 0;
    }
    int run = 0;
    #pragma unroll
    for (int j = 0; j < 16; ++j) { int c = v[j]; v[j] = run; run += c; }
    int lane = t & 63, wid = t >> 6;
    int incl = run;
    #pragma unroll
    for (int o = 1; o < 64; o <<= 1) { int u = __shfl_up(incl, o); if (lane >= o) incl += u; }
    __shared__ int wtot[4], wbase[4];
    if (lane == 63) wtot[wid] = incl;
    __syncthreads();
    if (t == 0) { int r = 0; for (int w = 0; w < 4; ++w) { wbase[w] = r; r += wtot[w]; } part[blockIdx.x] = r; }
    __syncthreads();
    int texcl = wbase[wid] + incl - run;
    if (ok) {
        #pragma unroll
        for (int j = 0; j < 16; ++j) offs[base + j] = texcl + v[j];
    }
}

// scanC with inlined partial-prefix; also seeds per-bucket cursors gcur[b]=offs[b*4096]
__global__ __launch_bounds__(256) void k_scanC(
    int* __restrict__ offs, const int* __restrict__ part, int* __restrict__ gcur)
{
    const int t = threadIdx.x;
    const int i = blockIdx.x * 256 + t;
    const int b0 = (blockIdx.x * 256) >> 12;
    int v = (t < b0) ? part[t] : 0;   // NSCAN <= 256
    #pragma unroll
    for (int o = 32; o > 0; o >>= 1) v += __shfl_xor(v, o);
    __shared__ int red[4];
    if ((t & 63) == 0) red[t >> 6] = v;
    __syncthreads();
    int pre = red[0] + red[1] + red[2] + red[3];
    if (i < NKEY) {
        int val = offs[i] + pre;
        offs[i] = val;
        if ((i & 4095) == 0) gcur[i >> 12] = val;
    } else if (i == NKEY) {
        offs[i] = N_EDGES;
    }
}

// ---------- binned scatter pass 1: group payloads by coarse bucket ----------
// payload = src<<12 | (dst&255)<<4 | et   (src < 2^16, so fits u32)
__global__ __launch_bounds__(256) void k_bin(
    const int* __restrict__ src, const int* __restrict__ dst, const int* __restrict__ et,
    int* __restrict__ gcur, unsigned int* __restrict__ scratch)
{
    __shared__ int cnt[NBKT], base[NBKT], lcur[NBKT];
    const int t = threadIdx.x;
    if (t < NBKT) cnt[t] = 0;
    __syncthreads();
    const int e0 = blockIdx.x * 4096;
    int dv[16];
    #pragma unroll
    for (int j = 0; j < 16; ++j) {
        int e = e0 + j * 256 + t;
        dv[j] = (e < N_EDGES) ? dst[e] : -1;
        if (dv[j] >= 0) atomicAdd(&cnt[dv[j] >> 8], 1);
    }
    __syncthreads();
    if (t < NBKT) {
        base[t] = cnt[t] ? atomicAdd(&gcur[t], cnt[t]) : 0;
        lcur[t] = 0;
    }
    __syncthreads();
    #pragma unroll
    for (int j = 0; j < 16; ++j) {
        int e = e0 + j * 256 + t;
        if (dv[j] >= 0) {
            int b = dv[j] >> 8;
            int pos = base[b] + atomicAdd(&lcur[b], 1);
            unsigned p = ((unsigned)src[e] << 12) | ((unsigned)(dv[j] & 255) << 4) | (unsigned)et[e];
            scratch[pos] = p;
        }
    }
}

// ---------- binned scatter pass 2: per-bucket fine scatter into csr ----------
__global__ __launch_bounds__(1024) void k_key(
    const int* __restrict__ offs, const unsigned int* __restrict__ scratch,
    unsigned int* __restrict__ csr)
{
    __shared__ int kcur[4096];
    const int t = threadIdx.x;
    const int k0 = blockIdx.x * 4096;
    #pragma unroll
    for (int j = 0; j < 4; ++j) {
        int i = t + j * 1024;
        if (k0 + i < NKEY) kcur[i] = offs[k0 + i];
    }
    __syncthreads();
    const int kend = (k0 + 4096 < NKEY) ? (k0 + 4096) : NKEY;
    const int E0 = offs[k0];
    const int E1 = offs[kend];
    for (int e = E0 + t; e < E1; e += 1024) {
        unsigned p = scratch[e];
        int pos = atomicAdd(&kcur[p & 0xFFFu], 1);
        csr[pos] = ((p >> 12) << 4) | (p & 15u);
    }
}

// ---------- fused layer: 32 nodes/block, 16 waves ----------
__global__ __launch_bounds__(1024, 8) void k_layer(
    const unsigned short* __restrict__ xbf_in,
    const int* __restrict__ offs,
    const unsigned int* __restrict__ csr,
    const unsigned short* __restrict__ wt,    // this layer, packed: [4][34][64][8] bf16
    const float* __restrict__ selfb,          // [64]
    unsigned short* __restrict__ xbf_out)
{
    alignas(16) __shared__ unsigned short S[TILE * SROW];
    const int tid = threadIdx.x, lane = tid & 63;
    const int wid = __builtin_amdgcn_readfirstlane(tid >> 6);
    const int nb = blockIdx.x * TILE;

    #pragma unroll
    for (int s = 0; s < 2; ++s) {
        unsigned int* Sr = reinterpret_cast<unsigned int*>(&S[(wid * 2 + s) * SROW]);
        #pragma unroll
        for (int i = 0; i < 8; ++i) Sr[lane + i * 64] = 0u;
        if (lane < 32) Sr[512 + lane] = 0u;
    }

    // phase A: per-node gather, 8-deep double-buffered pipeline
    #pragma unroll 1
    for (int s = 0; s < 2; ++s) {
        const int nl = wid * 2 + s;
        const int node = nb + nl;
        if (node >= N_NODES) break;
        const int A = offs[node * 16];
        const int B = offs[node * 16 + 16];
        S[nl * SROW + 1024 + lane] = xbf_in[(size_t)node * 64 + lane];
        const int deg = B - A;
        if (deg <= 0) continue;
        const float inv = 1.0f / (float)(deg > 1 ? deg : 1);

        unsigned c0[8], c1[8];
        float x0[8], x1[8];
        int cur = -1;
        float acc = 0.f;

        auto loadb = [&](unsigned (&cv)[8], float (&xv)[8], int eb) {
            #pragma unroll
            for (int j = 0; j < 8; ++j) {
                int idx = eb + j;
                idx = idx < B - 1 ? idx : B - 1;
                cv[j] = csr[idx];
            }
            #pragma unroll
            for (int j = 0; j < 8; ++j)
                xv[j] = bf2f(xbf_in[(size_t)(cv[j] >> 4) * 64 + lane]);
        };
        auto accum = [&](unsigned (&cv)[8], float (&xv)[8], int m) {
            #pragma unroll
            for (int j = 0; j < 8; ++j) {
                if (j < m) {
                    int rj = (int)(cv[j] & 15u);
                    if (rj != cur) {
                        if (cur >= 0) S[nl * SROW + cur * 64 + lane] = f2bf(acc * inv);
                        cur = rj;
                        acc = 0.f;
                    }
                    acc += xv[j];
                }
            }
        };

        int e0 = A;
        int m0 = deg > 8 ? 8 : deg;
        loadb(c0, x0, e0);
        for (;;) {
            int e1 = e0 + 8;
            int m1 = B - e1;
            m1 = m1 > 8 ? 8 : m1;
            if (m1 > 0) loadb(c1, x1, e1);
            accum(c0, x0, m0);
            if (m1 <= 0) break;
            int e2 = e1 + 8;
            m0 = B - e2;
            m0 = m0 > 8 ? 8 : m0;
            if (m0 > 0) loadb(c0, x0, e2);
            accum(c1, x1, m1);
            if (m0 <= 0) break;
            e0 = e2;
        }
        if (cur >= 0) S[nl * SROW + cur * 64 + lane] = f2bf(acc * inv);
    }
    __syncthreads();

    // phase B: wave = (g, kq); K-quarters {9,9,8,8}; both m-tiles per wave
    const int g = wid & 3, kq = wid >> 2;
    const int t0 = kq * 8 + (kq < 2 ? kq : 2);   // 0,9,18,26
    const int tn = kq < 2 ? 9 : 8;
    const int colg = lane & 15, kg = lane >> 4;
    f32x4 acc0 = {0.f, 0.f, 0.f, 0.f};
    f32x4 acc1 = {0.f, 0.f, 0.f, 0.f};
    const unsigned short* wb = wt + (size_t)g * (NKB * 512) + (size_t)lane * 8 + (size_t)t0 * 512;
    const unsigned short* sa0 = &S[colg * SROW + kg * 8 + t0 * 32];
    const unsigned short* sa1 = &S[(16 + colg) * SROW + kg * 8 + t0 * 32];
    #pragma unroll 1
    for (int t = 0; t < tn; ++t) {
        bf16x8 b  = *reinterpret_cast<const bf16x8*>(wb + (size_t)t * 512);
        bf16x8 a0 = *reinterpret_cast<const bf16x8*>(sa0 + t * 32);
        bf16x8 a1 = *reinterpret_cast<const bf16x8*>(sa1 + t * 32);
        acc0 = __builtin_amdgcn_mfma_f32_16x16x32_bf16(a0, b, acc0, 0, 0, 0);
        acc1 = __builtin_amdgcn_mfma_f32_16x16x32_bf16(a1, b, acc1, 0, 0, 0);
    }
    __syncthreads();
    float4* scr = reinterpret_cast<float4*>(S);
    if (kq > 0) {
        int base = ((kq - 1) * 4 + g) * 128 + lane;
        scr[base]      = make_float4(acc0[0], acc0[1], acc0[2], acc0[3]);
        scr[base + 64] = make_float4(acc1[0], acc1[1], acc1[2], acc1[3]);
    }
    __syncthreads();
    if (kq == 0) {
        #pragma unroll
        for (int p = 0; p < 3; ++p) {
            int base = (p * 4 + g) * 128 + lane;
            float4 q0 = scr[base], q1 = scr[base + 64];
            acc0[0] += q0.x; acc0[1] += q0.y; acc0[2] += q0.z; acc0[3] += q0.w;
            acc1[0] += q1.x; acc1[1] += q1.y; acc1[2] += q1.z; acc1[3] += q1.w;
        }
        const int col = g * 16 + colg;
        const float sb = selfb[col];
        #pragma unroll
        for (int j = 0; j < 4; ++j) {
            int n0 = nb + kg * 4 + j;
            float v0 = acc0[j] + sb;
            v0 = v0 > 0.f ? v0 : 0.f;
            if (n0 < N_NODES) xbf_out[(size_t)n0 * 64 + col] = f2bf(v0);
            int n1 = nb + 16 + kg * 4 + j;
            float v1 = acc1[j] + sb;
            v1 = v1 > 0.f ? v1 : 0.f;
            if (n1 < N_NODES) xbf_out[(size_t)n1 * 64 + col] = f2bf(v1);
        }
    }
}

// ---------- scoring (reads bf16 x) ----------
__global__ __launch_bounds__(256) void k_score(
    const unsigned short* __restrict__ x, const int* __restrict__ heads,
    const int* __restrict__ rels, const int* __restrict__ tails,
    const float* __restrict__ rel_emb, const float* __restrict__ w1,
    const float* __restrict__ b1, const float* __restrict__ w2,
    const float* __restrict__ b2, float* __restrict__ out)
{
    int q = blockIdx.x * 4 + (threadIdx.x >> 6);
    if (q >= N_Q) return;
    int lane = threadIdx.x & 63;
    float zh = bf2f(x[(size_t)heads[q] * 64 + lane]);
    float zt = bf2f(x[(size_t)tails[q] * 64 + lane]);
    float re = rel_emb[(size_t)rels[q] * 64 + lane];
    float acc = b1[lane];
    #pragma unroll 8
    for (int k = 0; k < 64; ++k)
        acc += bcast_lane(zh, k) * w1[k * 64 + lane];
    #pragma unroll 8
    for (int k = 0; k < 64; ++k)
        acc += bcast_lane(zt, k) * w1[(64 + k) * 64 + lane];
    #pragma unroll 8
    for (int k = 0; k < 64; ++k)
        acc += bcast_lane(re, k) * w1[(128 + k) * 64 + lane];
    float h = acc > 0.f ? acc : 0.f;
    float p = h * w2[lane];
    #pragma unroll
    for (int off = 32; off > 0; off >>= 1) p += __shfl_xor(p, off);
    if (lane == 0) out[q] = p + b2[0];
}

// ---------- launch ----------
extern "C" void kernel_launch(void* const* d_in, const int* in_sizes, int n_in,
                              void* d_out, int out_size, void* d_ws, size_t ws_size,
                              hipStream_t stream)
{
    const float* node_feat = (const float*)d_in[0];
    const int* edge_index  = (const int*)d_in[1];
    const int* edge_type   = (const int*)d_in[2];
    const int* heads       = (const int*)d_in[3];
    const int* rels        = (const int*)d_in[4];
    const int* tails       = (const int*)d_in[5];
    const float* in_w      = (const float*)d_in[6];
    const float* in_b      = (const float*)d_in[7];
    const float* rel_w     = (const float*)d_in[8];
    const float* self_w    = (const float*)d_in[9];
    const float* self_b    = (const float*)d_in[10];
    const float* rel_emb   = (const float*)d_in[11];
    const float* sc_w1     = (const float*)d_in[12];
    const float* sc_b1     = (const float*)d_in[13];
    const float* sc_w2     = (const float*)d_in[14];
    const float* sc_b2     = (const float*)d_in[15];
    float* out = (float*)d_out;

    char* ws = (char*)d_ws;
    size_t off = 0;
    auto alloc = [&](size_t bytes) -> void* {
        void* p = ws + off;
        off = (off + bytes + 255) & ~(size_t)255;
        return p;
    };
    unsigned short* xbf_a = (unsigned short*)alloc((size_t)N_NODES * 64 * 2);
    unsigned short* xbf_b = (unsigned short*)alloc((size_t)N_NODES * 64 * 2);
    int* cnt              = (int*)alloc((size_t)NKEY * 4);
    int* offs             = (int*)alloc((size_t)(NKEY + 1) * 4);
    unsigned int* scratch = (unsigned int*)alloc((size_t)N_EDGES * 4);
    unsigned int* csr     = (unsigned int*)alloc((size_t)N_EDGES * 4);
    unsigned short* wt    = (unsigned short*)alloc((size_t)2 * WTL * 2);
    int* part             = (int*)alloc(1024);
    int* gcur             = (int*)alloc(NBKT * 4);

    const int* src = edge_index;
    const int* dst = edge_index + N_EDGES;

    k_prep<<<NB_PROJ + NB_WPREP + NB_ZERO, 256, 0, stream>>>(
        node_feat, in_w, in_b, xbf_a, rel_w, self_w, wt, cnt);
    k_hist16<<<(N_EDGES + 255) / 256, 256, 0, stream>>>(dst, edge_type, cnt);
    k_scanA<<<NSCAN, 256, 0, stream>>>(cnt, offs, part);
    k_scanC<<<(NKEY + 1 + 255) / 256, 256, 0, stream>>>(offs, part, gcur);
    k_bin<<<(N_EDGES + 4095) / 4096, 256, 0, stream>>>(src, dst, edge_type, gcur, scratch);
    k_key<<<NBKT, 1024, 0, stream>>>(offs, scratch, csr);

    for (int l = 0; l < 2; ++l) {
        const unsigned short* xin = (l == 0) ? xbf_a : xbf_b;
        unsigned short* xout = (l == 0) ? xbf_b : xbf_a;
        k_layer<<<(N_NODES + TILE - 1) / TILE, 1024, 0, stream>>>(
            xin, offs, csr, wt + (size_t)l * WTL, self_b + l * 64, xout);
    }
    k_score<<<(N_Q + 3) / 4, 256, 0, stream>>>(xbf_a, heads, rels, tails, rel_emb,
                                               sc_w1, sc_b1, sc_w2, sc_b2, out);
}

// Round 11
// 154.633 us; speedup vs baseline: 1.4496x; 1.2145x over previous
//
#include <hip/hip_runtime.h>
#include <hip/hip_bf16.h>
#include <cstdint>
#include <cstddef>

#define N_NODES 50000
#define N_EDGES 800000
#define DIM 64
#define N_REL 16
#define N_Q 8192
#define NKEY (N_NODES * 16)
#define KDIM 1088   // 16 relations * 64 + 64 self
#define SROW 1096   // padded LDS row in bf16 elems
#define TILE 32     // nodes per block (2 per wave)
#define NKB 34      // K blocks of 32 (KDIM/32)
#define WTL (4 * NKB * 512)  // per-layer packed wt elems
#define NBKT 196    // coarse buckets (dst>>8)

// fused-prep grid partition
#define NB_PROJ 12500            // 50000*64/256
#define NB_WPREP 544             // 2*WTL/256

typedef __attribute__((ext_vector_type(8))) short bf16x8;
typedef __attribute__((ext_vector_type(4))) float f32x4;

__device__ __forceinline__ float bcast_lane(float v, int l) {
    return __int_as_float(__builtin_amdgcn_readlane(__float_as_int(v), l));
}
__device__ __forceinline__ unsigned short f2bf(float f) {
    unsigned int b = __float_as_uint(f);
    return (unsigned short)((b + 0x7FFFu + ((b >> 16) & 1u)) >> 16);
}
__device__ __forceinline__ float bf2f(unsigned short u) {
    return __uint_as_float(((unsigned int)u) << 16);
}

// ---------- fused prep: input projection + weight pack + btot zero ----------
__global__ __launch_bounds__(256) void k_prep(
    const float* __restrict__ nf, const float* __restrict__ inw,
    const float* __restrict__ inb, unsigned short* __restrict__ xbf,
    const float* __restrict__ rel_w, const float* __restrict__ self_w,
    unsigned short* __restrict__ wt, int* __restrict__ btot)
{
    const int b = blockIdx.x, tid = threadIdx.x;
    if (b < NB_PROJ) {
        int t = b * 256 + tid;
        int n = t >> 6, o = t & 63;
        float4 f = *reinterpret_cast<const float4*>(nf + (size_t)n * 4);
        float a = inb[o] + f.x * inw[o] + f.y * inw[64 + o] + f.z * inw[128 + o] + f.w * inw[192 + o];
        xbf[t] = f2bf(a > 0.f ? a : 0.f);
    } else if (b < NB_PROJ + NB_WPREP) {
        int i = (b - NB_PROJ) * 256 + tid;
        int j = i & 7;
        int lane = (i >> 3) & 63;
        int rest = i >> 9;          // l*136 + g*34 + t
        int t = rest % NKB;
        int gl = rest / NKB;
        int g = gl & 3;
        int l = gl >> 2;
        int col = g * 16 + (lane & 15);
        int k = t * 32 + (lane >> 4) * 8 + j;
        float v;
        if (k < 1024) {
            int r = k >> 6, d = k & 63;
            v = rel_w[(((size_t)l * 16 + r) * 64 + d) * 64 + col];
        } else {
            int d = k - 1024;
            v = self_w[((size_t)l * 64 + d) * 64 + col];
        }
        wt[i] = f2bf(v);
    } else {
        if (tid < NBKT) btot[tid] = 0;
    }
}

// ---------- bucket pipeline ----------
// pass A: coarse per-bucket counts
__global__ __launch_bounds__(256) void k_binA(
    const int* __restrict__ dst, int* __restrict__ btot)
{
    __shared__ int h[NBKT];
    const int t = threadIdx.x;
    if (t < NBKT) h[t] = 0;
    __syncthreads();
    const int e0 = blockIdx.x * 4096;
    #pragma unroll
    for (int j = 0; j < 16; ++j) {
        int e = e0 + j * 256 + t;
        if (e < N_EDGES) atomicAdd(&h[dst[e] >> 8], 1);
    }
    __syncthreads();
    if (t < NBKT && h[t]) atomicAdd(&btot[t], h[t]);
}

// pass S: scan 196 bucket totals -> bbase[0..196], seed gcur
__global__ __launch_bounds__(256) void k_binS(
    const int* __restrict__ btot, int* __restrict__ bbase, int* __restrict__ gcur)
{
    const int t = threadIdx.x;
    int v = (t < NBKT) ? btot[t] : 0;
    const int lane = t & 63, wid = t >> 6;
    int incl = v;
    #pragma unroll
    for (int o = 1; o < 64; o <<= 1) { int u = __shfl_up(incl, o); if (lane >= o) incl += u; }
    __shared__ int ws[4];
    if (lane == 63) ws[wid] = incl;
    __syncthreads();
    int wb = 0;
    #pragma unroll
    for (int w = 0; w < 4; ++w) if (w < wid) wb += ws[w];
    int excl = wb + incl - v;
    if (t < NBKT) { bbase[t] = excl; gcur[t] = excl; }
    if (t == NBKT - 1) bbase[NBKT] = excl + v;
}

// pass B: scatter payloads grouped by coarse bucket
// payload = src<<12 | (dst&255)<<4 | et
__global__ __launch_bounds__(256) void k_binB(
    const int* __restrict__ src, const int* __restrict__ dst, const int* __restrict__ et,
    int* __restrict__ gcur, unsigned int* __restrict__ scratch)
{
    __shared__ int cnt[NBKT], base[NBKT], lcur[NBKT];
    const int t = threadIdx.x;
    if (t < NBKT) cnt[t] = 0;
    __syncthreads();
    const int e0 = blockIdx.x * 4096;
    int dv[16];
    #pragma unroll
    for (int j = 0; j < 16; ++j) {
        int e = e0 + j * 256 + t;
        dv[j] = (e < N_EDGES) ? dst[e] : -1;
        if (dv[j] >= 0) atomicAdd(&cnt[dv[j] >> 8], 1);
    }
    __syncthreads();
    if (t < NBKT) {
        base[t] = cnt[t] ? atomicAdd(&gcur[t], cnt[t]) : 0;
        lcur[t] = 0;
    }
    __syncthreads();
    #pragma unroll
    for (int j = 0; j < 16; ++j) {
        int e = e0 + j * 256 + t;
        if (dv[j] >= 0) {
            int b = dv[j] >> 8;
            int pos = base[b] + atomicAdd(&lcur[b], 1);
            unsigned p = ((unsigned)src[e] << 12) | ((unsigned)(dv[j] & 255) << 4) | (unsigned)et[e];
            scratch[pos] = p;
        }
    }
}

// pass K: per bucket: fine histogram + local scan -> offs; local scatter -> csr
// csr entry = (src<<7) | et   (byte offset of x row = entry & ~127)
__global__ __launch_bounds__(1024) void k_key2(
    const int* __restrict__ bbase, const unsigned int* __restrict__ scratch,
    int* __restrict__ offs, unsigned int* __restrict__ csr)
{
    __shared__ int hist[4096];
    __shared__ int wsum[16];
    const int t = threadIdx.x;
    const int b = blockIdx.x;
    const int k0 = b * 4096;
    #pragma unroll
    for (int j = 0; j < 4; ++j) hist[t + j * 1024] = 0;
    __syncthreads();
    const int E0 = bbase[b], E1 = bbase[b + 1];
    for (int e = E0 + t; e < E1; e += 1024)
        atomicAdd(&hist[scratch[e] & 0xFFFu], 1);
    __syncthreads();
    int4 h4 = *reinterpret_cast<int4*>(&hist[t * 4]);
    int run = h4.x + h4.y + h4.z + h4.w;
    const int lane = t & 63, wid = t >> 6;
    int incl = run;
    #pragma unroll
    for (int o = 1; o < 64; o <<= 1) { int u = __shfl_up(incl, o); if (lane >= o) incl += u; }
    if (lane == 63) wsum[wid] = incl;
    __syncthreads();
    if (wid == 0) {
        int wv = (lane < 16) ? wsum[lane] : 0;
        #pragma unroll
        for (int o = 1; o < 16; o <<= 1) { int u = __shfl_up(wv, o); if (lane >= o) wv += u; }
        if (lane < 16) wsum[lane] = wv;
    }
    __syncthreads();
    int texcl = (wid ? wsum[wid - 1] : 0) + incl - run;
    int4 cur;
    cur.x = E0 + texcl;
    cur.y = cur.x + h4.x;
    cur.z = cur.y + h4.y;
    cur.w = cur.z + h4.z;
    *reinterpret_cast<int4*>(&hist[t * 4]) = cur;
    if (k0 + t * 4 < NKEY)
        *reinterpret_cast<int4*>(&offs[k0 + t * 4]) = cur;
    if (b == NBKT - 1 && t == 0) offs[NKEY] = N_EDGES;
    __syncthreads();
    for (int e = E0 + t; e < E1; e += 1024) {
        unsigned p = scratch[e];
        int pos = atomicAdd(&hist[p & 0xFFFu], 1);
        csr[pos] = ((p >> 12) << 7) | (p & 15u);
    }
}

// ---------- fused layer: 32 nodes/block, 16 waves ----------
__global__ __launch_bounds__(1024, 8) void k_layer(
    const unsigned short* __restrict__ xbf_in,
    const int* __restrict__ offs,
    const unsigned int* __restrict__ csr,
    const unsigned short* __restrict__ wt,    // this layer, packed: [4][34][64][8] bf16
    const float* __restrict__ selfb,          // [64]
    unsigned short* __restrict__ xbf_out)
{
    alignas(16) __shared__ unsigned short S[TILE * SROW];
    const int tid = threadIdx.x, lane = tid & 63;
    const int wid = __builtin_amdgcn_readfirstlane(tid >> 6);
    const int nb = blockIdx.x * TILE;

    #pragma unroll
    for (int s = 0; s < 2; ++s) {
        unsigned int* Sr = reinterpret_cast<unsigned int*>(&S[(wid * 2 + s) * SROW]);
        #pragma unroll
        for (int i = 0; i < 8; ++i) Sr[lane + i * 64] = 0u;
        if (lane < 32) Sr[512 + lane] = 0u;
    }

    // phase A: per-node gather, 8-deep double-buffered pipeline
    #pragma unroll 1
    for (int s = 0; s < 2; ++s) {
        const int nl = wid * 2 + s;
        const int node = nb + nl;
        if (node >= N_NODES) break;
        const int A = offs[node * 16];
        const int B = offs[node * 16 + 16];
        S[nl * SROW + 1024 + lane] = xbf_in[(size_t)node * 64 + lane];
        const int deg = B - A;
        if (deg <= 0) continue;
        const float inv = 1.0f / (float)(deg > 1 ? deg : 1);

        const unsigned loff = (unsigned)(lane << 1);
        unsigned c0[8], c1[8];
        float x0[8], x1[8];
        int cur = -1;
        float acc = 0.f;

        auto loadb = [&](unsigned (&cv)[8], float (&xv)[8], int eb) {
            #pragma unroll
            for (int j = 0; j < 8; ++j) {
                int idx = eb + j;
                idx = idx < B - 1 ? idx : B - 1;
                cv[j] = csr[idx];
            }
            #pragma unroll
            for (int j = 0; j < 8; ++j) {
                unsigned off = (cv[j] & 0xFFFFFF80u) | loff;
                xv[j] = bf2f(*reinterpret_cast<const unsigned short*>(
                    reinterpret_cast<const char*>(xbf_in) + off));
            }
        };
        auto accum = [&](unsigned (&cv)[8], float (&xv)[8], int m) {
            #pragma unroll
            for (int j = 0; j < 8; ++j) {
                if (j < m) {
                    int rj = (int)(cv[j] & 15u);
                    if (rj != cur) {
                        if (cur >= 0) S[nl * SROW + cur * 64 + lane] = f2bf(acc * inv);
                        cur = rj;
                        acc = 0.f;
                    }
                    acc += xv[j];
                }
            }
        };

        int e0 = A;
        int m0 = deg > 8 ? 8 : deg;
        loadb(c0, x0, e0);
        for (;;) {
            int e1 = e0 + 8;
            int m1 = B - e1;
            m1 = m1 > 8 ? 8 : m1;
            if (m1 > 0) loadb(c1, x1, e1);
            accum(c0, x0, m0);
            if (m1 <= 0) break;
            int e2 = e1 + 8;
            m0 = B - e2;
            m0 = m0 > 8 ? 8 : m0;
            if (m0 > 0) loadb(c0, x0, e2);
            accum(c1, x1, m1);
            if (m0 <= 0) break;
            e0 = e2;
        }
        if (cur >= 0) S[nl * SROW + cur * 64 + lane] = f2bf(acc * inv);
    }
    __syncthreads();

    // phase B: wave = (g, kq); K-quarters {9,9,8,8}; both m-tiles per wave
    const int g = wid & 3, kq = wid >> 2;
    const int t0 = kq * 8 + (kq < 2 ? kq : 2);   // 0,9,18,26
    const int tn = kq < 2 ? 9 : 8;
    const int colg = lane & 15, kg = lane >> 4;
    f32x4 acc0 = {0.f, 0.f, 0.f, 0.f};
    f32x4 acc1 = {0.f, 0.f, 0.f, 0.f};
    const unsigned short* wb = wt + (size_t)g * (NKB * 512) + (size_t)lane * 8 + (size_t)t0 * 512;
    const unsigned short* sa0 = &S[colg * SROW + kg * 8 + t0 * 32];
    const unsigned short* sa1 = &S[(16 + colg) * SROW + kg * 8 + t0 * 32];
    #pragma unroll 1
    for (int t = 0; t < tn; ++t) {
        bf16x8 b  = *reinterpret_cast<const bf16x8*>(wb + (size_t)t * 512);
        bf16x8 a0 = *reinterpret_cast<const bf16x8*>(sa0 + t * 32);
        bf16x8 a1 = *reinterpret_cast<const bf16x8*>(sa1 + t * 32);
        acc0 = __builtin_amdgcn_mfma_f32_16x16x32_bf16(a0, b, acc0, 0, 0, 0);
        acc1 = __builtin_amdgcn_mfma_f32_16x16x32_bf16(a1, b, acc1, 0, 0, 0);
    }
    __syncthreads();
    float4* scr = reinterpret_cast<float4*>(S);
    if (kq > 0) {
        int base = ((kq - 1) * 4 + g) * 128 + lane;
        scr[base]      = make_float4(acc0[0], acc0[1], acc0[2], acc0[3]);
        scr[base + 64] = make_float4(acc1[0], acc1[1], acc1[2], acc1[3]);
    }
    __syncthreads();
    if (kq == 0) {
        #pragma unroll
        for (int p = 0; p < 3; ++p) {
            int base = (p * 4 + g) * 128 + lane;
            float4 q0 = scr[base], q1 = scr[base + 64];
            acc0[0] += q0.x; acc0[1] += q0.y; acc0[2] += q0.z; acc0[3] += q0.w;
            acc1[0] += q1.x; acc1[1] += q1.y; acc1[2] += q1.z; acc1[3] += q1.w;
        }
        const int col = g * 16 + colg;
        const float sb = selfb[col];
        #pragma unroll
        for (int j = 0; j < 4; ++j) {
            int n0 = nb + kg * 4 + j;
            float v0 = acc0[j] + sb;
            v0 = v0 > 0.f ? v0 : 0.f;
            if (n0 < N_NODES) xbf_out[(size_t)n0 * 64 + col] = f2bf(v0);
            int n1 = nb + 16 + kg * 4 + j;
            float v1 = acc1[j] + sb;
            v1 = v1 > 0.f ? v1 : 0.f;
            if (n1 < N_NODES) xbf_out[(size_t)n1 * 64 + col] = f2bf(v1);
        }
    }
}

// ---------- scoring (reads bf16 x) ----------
__global__ __launch_bounds__(256) void k_score(
    const unsigned short* __restrict__ x, const int* __restrict__ heads,
    const int* __restrict__ rels, const int* __restrict__ tails,
    const float* __restrict__ rel_emb, const float* __restrict__ w1,
    const float* __restrict__ b1, const float* __restrict__ w2,
    const float* __restrict__ b2, float* __restrict__ out)
{
    int q = blockIdx.x * 4 + (threadIdx.x >> 6);
    if (q >= N_Q) return;
    int lane = threadIdx.x & 63;
    float zh = bf2f(x[(size_t)heads[q] * 64 + lane]);
    float zt = bf2f(x[(size_t)tails[q] * 64 + lane]);
    float re = rel_emb[(size_t)rels[q] * 64 + lane];
    float acc = b1[lane];
    #pragma unroll 8
    for (int k = 0; k < 64; ++k)
        acc += bcast_lane(zh, k) * w1[k * 64 + lane];
    #pragma unroll 8
    for (int k = 0; k < 64; ++k)
        acc += bcast_lane(zt, k) * w1[(64 + k) * 64 + lane];
    #pragma unroll 8
    for (int k = 0; k < 64; ++k)
        acc += bcast_lane(re, k) * w1[(128 + k) * 64 + lane];
    float h = acc > 0.f ? acc : 0.f;
    float p = h * w2[lane];
    #pragma unroll
    for (int off = 32; off > 0; off >>= 1) p += __shfl_xor(p, off);
    if (lane == 0) out[q] = p + b2[0];
}

// ---------- launch ----------
extern "C" void kernel_launch(void* const* d_in, const int* in_sizes, int n_in,
                              void* d_out, int out_size, void* d_ws, size_t ws_size,
                              hipStream_t stream)
{
    const float* node_feat = (const float*)d_in[0];
    const int* edge_index  = (const int*)d_in[1];
    const int* edge_type   = (const int*)d_in[2];
    const int* heads       = (const int*)d_in[3];
    const int* rels        = (const int*)d_in[4];
    const int* tails       = (const int*)d_in[5];
    const float* in_w      = (const float*)d_in[6];
    const float* in_b      = (const float*)d_in[7];
    const float* rel_w     = (const float*)d_in[8];
    const float* self_w    = (const float*)d_in[9];
    const float* self_b    = (const float*)d_in[10];
    const float* rel_emb   = (const float*)d_in[11];
    const float* sc_w1     = (const float*)d_in[12];
    const float* sc_b1     = (const float*)d_in[13];
    const float* sc_w2     = (const float*)d_in[14];
    const float* sc_b2     = (const float*)d_in[15];
    float* out = (float*)d_out;

    char* ws = (char*)d_ws;
    size_t off = 0;
    auto alloc = [&](size_t bytes) -> void* {
        void* p = ws + off;
        off = (off + bytes + 255) & ~(size_t)255;
        return p;
    };
    unsigned short* xbf_a = (unsigned short*)alloc((size_t)N_NODES * 64 * 2);
    unsigned short* xbf_b = (unsigned short*)alloc((size_t)N_NODES * 64 * 2);
    int* offs             = (int*)alloc((size_t)(NKEY + 1) * 4);
    unsigned int* scratch = (unsigned int*)alloc((size_t)N_EDGES * 4);
    unsigned int* csr     = (unsigned int*)alloc((size_t)N_EDGES * 4);
    unsigned short* wt    = (unsigned short*)alloc((size_t)2 * WTL * 2);
    int* btot             = (int*)alloc(NBKT * 4);
    int* bbase            = (int*)alloc((NBKT + 1) * 4);
    int* gcur             = (int*)alloc(NBKT * 4);

    const int* src = edge_index;
    const int* dst = edge_index + N_EDGES;

    k_prep<<<NB_PROJ + NB_WPREP + 1, 256, 0, stream>>>(
        node_feat, in_w, in_b, xbf_a, rel_w, self_w, wt, btot);
    k_binA<<<(N_EDGES + 4095) / 4096, 256, 0, stream>>>(dst, btot);
    k_binS<<<1, 256, 0, stream>>>(btot, bbase, gcur);
    k_binB<<<(N_EDGES + 4095) / 4096, 256, 0, stream>>>(src, dst, edge_type, gcur, scratch);
    k_key2<<<NBKT, 1024, 0, stream>>>(bbase, scratch, offs, csr);

    for (int l = 0; l < 2; ++l) {
        const unsigned short* xin = (l == 0) ? xbf_a : xbf_b;
        unsigned short* xout = (l == 0) ? xbf_b : xbf_a;
        k_layer<<<(N_NODES + TILE - 1) / TILE, 1024, 0, stream>>>(
            xin, offs, csr, wt + (size_t)l * WTL, self_b + l * 64, xout);
    }
    k_score<<<(N_Q + 3) / 4, 256, 0, stream>>>(xbf_a, heads, rels, tails, rel_emb,
                                               sc_w1, sc_b1, sc_w2, sc_b2, out);
}